// Round 2
// baseline (1479.773 us; speedup 1.0000x reference)
//
#include <hip/hip_runtime.h>

#define BB 64
#define TT 2048
#define DD 512
#define UU 32

// ---------------------------------------------------------------------------
// K1: logits[b,t,u] = sum_k x[b,t,k]*kernel[k,u] + bias[u]
// grid 512 x 256 threads. BM=256 rows/block, BK=32.
// ---------------------------------------------------------------------------
__global__ __launch_bounds__(256) void k1_logits(const float* __restrict__ x,
                                                 const float* __restrict__ w,
                                                 const float* __restrict__ bias,
                                                 float* __restrict__ out) {
  __shared__ float xs[256 * 34];
  __shared__ float wsh[32 * 36];
  const int tid = threadIdx.x;
  const long row0 = (long)blockIdx.x * 256;
  const int tr = tid >> 2;         // 0..63
  const int tc = tid & 3;          // 0..3
  const int ubase = tc * 8;
  const int sr = tid >> 3;         // staging row within pass (0..31)
  const int sc = (tid & 7) * 4;    // staging col (0,4,..,28)

  float acc[4][8];
#pragma unroll
  for (int i = 0; i < 4; ++i)
#pragma unroll
    for (int j = 0; j < 8; ++j) acc[i][j] = 0.0f;

  for (int kc = 0; kc < DD; kc += 32) {
#pragma unroll
    for (int p = 0; p < 8; ++p) {
      const int r = p * 32 + sr;
      const float4 v = *(const float4*)(x + (row0 + r) * DD + kc + sc);
      *(float2*)(&xs[r * 34 + sc]) = make_float2(v.x, v.y);
      *(float2*)(&xs[r * 34 + sc + 2]) = make_float2(v.z, v.w);
    }
    {
      const int k = tid >> 3;
      const int uu4 = (tid & 7) * 4;
      const float4 v = *(const float4*)(w + (size_t)(kc + k) * UU + uu4);
      *(float4*)(&wsh[k * 36 + uu4]) = v;
    }
    __syncthreads();
#pragma unroll
    for (int k = 0; k < 32; ++k) {
      const float4 w0 = *(const float4*)(&wsh[k * 36 + ubase]);
      const float4 w1 = *(const float4*)(&wsh[k * 36 + ubase + 4]);
      const float wv[8] = {w0.x, w0.y, w0.z, w0.w, w1.x, w1.y, w1.z, w1.w};
#pragma unroll
      for (int i = 0; i < 4; ++i) {
        const float xv = xs[(tr + 64 * i) * 34 + k];
#pragma unroll
        for (int j = 0; j < 8; ++j) acc[i][j] = fmaf(xv, wv[j], acc[i][j]);
      }
    }
    __syncthreads();
  }
  float bv[8];
#pragma unroll
  for (int j = 0; j < 8; ++j) bv[j] = bias[ubase + j];
#pragma unroll
  for (int i = 0; i < 4; ++i) {
    const long row = row0 + tr + 64 * i;
    float4 o0, o1;
    o0.x = acc[i][0] + bv[0]; o0.y = acc[i][1] + bv[1];
    o0.z = acc[i][2] + bv[2]; o0.w = acc[i][3] + bv[3];
    o1.x = acc[i][4] + bv[4]; o1.y = acc[i][5] + bv[5];
    o1.z = acc[i][6] + bv[6]; o1.w = acc[i][7] + bv[7];
    *(float4*)(out + row * UU + ubase) = o0;
    *(float4*)(out + row * UU + ubase + 4) = o1;
  }
}

// ---------------------------------------------------------------------------
// K2: Viterbi forward, one wave per chain. DEFERRED-COMBINE scheme:
// lane (u,h) carries PARTIAL p = max over v in [16h,16h+16) of
// (alpha_prev[v]+T[v][u]) + l_t[u]. True alpha[v] = max(p@lane v, p@lane v+32).
// Next step's gather fetches BOTH partials per v (2 bpermutes) and folds with
// max — so only ONE LDS latency sits on the recurrence (no serial shfl).
// Combined alpha rows (needed by K3/K4) are stored via an off-chain shfl_xor.
// Logits prefetched 16 rows deep, double-buffered in registers.
// ---------------------------------------------------------------------------
__global__ __launch_bounds__(64) void k2_forward(float* __restrict__ lb,
                                                 const float* __restrict__ trans,
                                                 const int* __restrict__ nwords,
                                                 float* __restrict__ score) {
  const int b = blockIdx.x;
  const int lane = threadIdx.x;
  const int u = lane & 31;
  const int h = lane >> 5;

  float tv[16];
#pragma unroll
  for (int i = 0; i < 16; ++i) tv[i] = trans[(h * 16 + i) * UU + u];

  float* base = lb + (size_t)b * TT * UU;
  const int nw = nwords[b];

  float p = base[u];  // row 0 = alpha0; both halves identical (max(a,a)=a)

  float bufA[16], bufB[16];
#pragma unroll
  for (int i = 0; i < 16; ++i) {
    int r = 1 + i; if (r > TT - 1) r = TT - 1;
    bufA[i] = base[(size_t)r * UU + u];
  }

#define K2_STEP(tval, lg)                                                     \
  {                                                                           \
    float m0 = -3.4e38f, m1 = -3.4e38f;                                       \
    _Pragma("unroll")                                                         \
    for (int i = 0; i < 16; ++i) {                                            \
      const int v = h * 16 + i;                                               \
      const int pa = __builtin_amdgcn_ds_bpermute(v << 2, __float_as_int(p)); \
      const int pb =                                                          \
          __builtin_amdgcn_ds_bpermute((v + 32) << 2, __float_as_int(p));     \
      const float c =                                                         \
          fmaxf(__int_as_float(pa), __int_as_float(pb)) + tv[i];              \
      if (i & 1) m1 = fmaxf(m1, c); else m0 = fmaxf(m0, c);                   \
    }                                                                         \
    p = fmaxf(m0, m1) + (lg);                                                 \
    const float smv = fmaxf(p, __shfl_xor(p, 32));                            \
    if (h == 0) base[(size_t)(tval)*UU + u] = smv;                            \
  }

  for (int tc = 1; tc < nw; tc += 32) {
    // prefetch bufB = rows [tc+16, tc+32) (clamped; physically in-bounds)
#pragma unroll
    for (int i = 0; i < 16; ++i) {
      int r = tc + 16 + i; if (r > TT - 1) r = TT - 1;
      bufB[i] = base[(size_t)r * UU + u];
    }
    // body A: steps tc .. tc+15
#pragma unroll
    for (int i = 0; i < 16; ++i) {
      const int t = tc + i;
      if (t < nw) K2_STEP(t, bufA[i]);
    }
    // prefetch bufA = rows [tc+32, tc+48)
#pragma unroll
    for (int i = 0; i < 16; ++i) {
      int r = tc + 32 + i; if (r > TT - 1) r = TT - 1;
      bufA[i] = base[(size_t)r * UU + u];
    }
    // body B: steps tc+16 .. tc+31
#pragma unroll
    for (int i = 0; i < 16; ++i) {
      const int t = tc + 16 + i;
      if (t < nw) K2_STEP(t, bufB[i]);
    }
  }
#undef K2_STEP

  // best_score = max_u alpha_{nw-1}[u]; combine halves then tree-reduce.
  float sm = fmaxf(p, __shfl_xor(p, 32));
#pragma unroll
  for (int s = 16; s; s >>= 1) sm = fmaxf(sm, __shfl_xor(sm, s));
  if (lane == 0) score[b] = sm;
}

// ---------------------------------------------------------------------------
// K3: backpointers, fully parallel from stored alpha rows.
// ---------------------------------------------------------------------------
__global__ __launch_bounds__(256) void k3_bp(const float* __restrict__ lb,
                                             const float* __restrict__ trans,
                                             const int* __restrict__ nwords,
                                             unsigned char* __restrict__ bp) {
  __shared__ float as[129 * 32];
  __shared__ float ts[32 * 32];
  const int b = blockIdx.x >> 4;
  const int c = blockIdx.x & 15;
  const int t0 = 128 * c;
  const int tid = threadIdx.x;
  const float* base = lb + (size_t)b * TT * UU;
  const int nw = nwords[b];

  for (int idx = tid; idx < 129 * 32; idx += 256) {
    const int gidx = (t0 - 1) * 32 + idx;
    as[idx] = (gidx >= 0 && gidx < TT * UU) ? base[gidx] : 0.0f;
  }
  for (int idx = tid; idx < 1024; idx += 256) ts[idx] = trans[idx];
  __syncthreads();

  const int u = tid & 31;
  const int tg = tid >> 5;
  unsigned char* bpu = bp + ((size_t)b * 32 + u) * TT;

#pragma unroll 1
  for (int q = 0; q < 4; ++q) {
    const int tl0 = tg * 16 + q * 4;
    unsigned int pack = 0;
#pragma unroll
    for (int e = 0; e < 4; ++e) {
      const int tl = tl0 + e;
      const int t = t0 + tl;
      int idx;
      if (t >= 1 && t < nw) {
        float m = as[tl * 32 + 0] + ts[0 * 32 + u];
        idx = 0;
#pragma unroll
        for (int v = 1; v < 32; ++v) {
          const float cv = as[tl * 32 + v] + ts[v * 32 + u];
          if (cv > m) { m = cv; idx = v; }
        }
      } else {
        idx = u;
      }
      pack |= ((unsigned int)idx) << (8 * e);
    }
    *(unsigned int*)(bpu + t0 + tl0) = pack;
  }
}

// ---------------------------------------------------------------------------
// K4: backtrace, one wave per chain; bp chunks held in VGPRs, tag via readlane.
// ---------------------------------------------------------------------------
__global__ __launch_bounds__(64) void k4_backtrace(const float* __restrict__ lb,
                                                   const unsigned char* __restrict__ bp,
                                                   const int* __restrict__ nwords,
                                                   int* __restrict__ pred) {
  const int b = blockIdx.x;
  const int lane = threadIdx.x;
  const int u = lane & 31;
  const int h = lane >> 5;
  const int nw = nwords[b];

  const float a = lb[((size_t)b * TT + (nw - 1)) * UU + u];
  float m = a;
#pragma unroll
  for (int s = 32; s; s >>= 1) m = fmaxf(m, __shfl_xor(m, s));
  const unsigned long long mask = __ballot(lane < 32 && a == m);
  int tag = __ffsll((unsigned long long)mask) - 1;
  tag = __builtin_amdgcn_readfirstlane(tag);

  int* predb = pred + b * TT;
  for (int p = nw - 1 + lane; p < TT; p += 64) predb[p] = tag;
  if (nw < 2) return;

  const unsigned char* bpb = bp + (size_t)b * 32 * TT;
  const int pcmax = (nw - 2) >> 6;
  const int thi_top = nw - 1;

  int wprev0 = 0;
  {
    const int toff = (pcmax + 1) * 64;
    if (toff < TT) wprev0 = *(const int*)(bpb + (size_t)u * TT + toff);
  }

  for (int pc = pcmax; pc >= 0; --pc) {
    int wreg[8];
#pragma unroll
    for (int j = 0; j < 8; ++j)
      wreg[j] = *(const int*)(bpb + (size_t)u * TT + pc * 64 + 4 * (h * 8 + j));
    const int thi = (pc == pcmax) ? thi_top : (pc * 64 + 64);
    int predv = 0;

    if (pc * 64 + 64 <= thi) {
      const int val = __builtin_amdgcn_readlane(wprev0, tag);
      tag = __builtin_amdgcn_readfirstlane(val & 0xFF);
      if (lane == 63) predv = tag;
    }
#pragma unroll
    for (int lt = 63; lt >= 1; --lt) {
      if (pc * 64 + lt <= thi) {
        const int d = lt >> 2, byte = lt & 3;
        const int hs = d >> 3, j = d & 7;
        const int val = __builtin_amdgcn_readlane(wreg[j], hs * 32 + tag);
        tag = __builtin_amdgcn_readfirstlane((val >> (8 * byte)) & 0xFF);
        if (lane == lt - 1) predv = tag;
      }
    }
    const int lim = thi - pc * 64;
    if (lane < lim) predb[pc * 64 + lane] = predv;
    wprev0 = wreg[0];
  }
}

// ---------------------------------------------------------------------------
extern "C" void kernel_launch(void* const* d_in, const int* in_sizes, int n_in,
                              void* d_out, int out_size, void* d_ws, size_t ws_size,
                              hipStream_t stream) {
  const float* x = (const float*)d_in[0];
  const int* nwords = (const int*)d_in[1];
  const float* kern = (const float*)d_in[2];
  const float* chain = (const float*)d_in[3];
  const float* bias = (const float*)d_in[4];

  float* logits = (float*)d_ws;                                        // 16 MB
  unsigned char* bp = (unsigned char*)d_ws + (size_t)BB * TT * UU * 4; // +4 MB

  int* pred = (int*)d_out;
  float* score = (float*)d_out + (size_t)BB * TT;

  k1_logits<<<dim3(512), dim3(256), 0, stream>>>(x, kern, bias, logits);
  k2_forward<<<dim3(BB), dim3(64), 0, stream>>>(logits, chain, nwords, score);
  k3_bp<<<dim3(BB * 16), dim3(256), 0, stream>>>(logits, chain, nwords, bp);
  k4_backtrace<<<dim3(BB), dim3(64), 0, stream>>>(logits, bp, nwords, pred);
}

// Round 3
// 688.461 us; speedup vs baseline: 2.1494x; 2.1494x over previous
//
#include <hip/hip_runtime.h>

#define BB 64
#define TT 2048
#define DD 512
#define UU 32

// ---------------------------------------------------------------------------
// K1: logits[b,t,u] = sum_k x[b,t,k]*kernel[k,u] + bias[u]
// grid 512 x 256 threads. BM=256 rows/block, BK=32.
// ---------------------------------------------------------------------------
__global__ __launch_bounds__(256) void k1_logits(const float* __restrict__ x,
                                                 const float* __restrict__ w,
                                                 const float* __restrict__ bias,
                                                 float* __restrict__ out) {
  __shared__ float xs[256 * 34];
  __shared__ float wsh[32 * 36];
  const int tid = threadIdx.x;
  const long row0 = (long)blockIdx.x * 256;
  const int tr = tid >> 2;         // 0..63
  const int tc = tid & 3;          // 0..3
  const int ubase = tc * 8;
  const int sr = tid >> 3;         // staging row within pass (0..31)
  const int sc = (tid & 7) * 4;    // staging col (0,4,..,28)

  float acc[4][8];
#pragma unroll
  for (int i = 0; i < 4; ++i)
#pragma unroll
    for (int j = 0; j < 8; ++j) acc[i][j] = 0.0f;

  for (int kc = 0; kc < DD; kc += 32) {
#pragma unroll
    for (int p = 0; p < 8; ++p) {
      const int r = p * 32 + sr;
      const float4 v = *(const float4*)(x + (row0 + r) * DD + kc + sc);
      *(float2*)(&xs[r * 34 + sc]) = make_float2(v.x, v.y);
      *(float2*)(&xs[r * 34 + sc + 2]) = make_float2(v.z, v.w);
    }
    {
      const int k = tid >> 3;
      const int uu4 = (tid & 7) * 4;
      const float4 v = *(const float4*)(w + (size_t)(kc + k) * UU + uu4);
      *(float4*)(&wsh[k * 36 + uu4]) = v;
    }
    __syncthreads();
#pragma unroll
    for (int k = 0; k < 32; ++k) {
      const float4 w0 = *(const float4*)(&wsh[k * 36 + ubase]);
      const float4 w1 = *(const float4*)(&wsh[k * 36 + ubase + 4]);
      const float wv[8] = {w0.x, w0.y, w0.z, w0.w, w1.x, w1.y, w1.z, w1.w};
#pragma unroll
      for (int i = 0; i < 4; ++i) {
        const float xv = xs[(tr + 64 * i) * 34 + k];
#pragma unroll
        for (int j = 0; j < 8; ++j) acc[i][j] = fmaf(xv, wv[j], acc[i][j]);
      }
    }
    __syncthreads();
  }
  float bv[8];
#pragma unroll
  for (int j = 0; j < 8; ++j) bv[j] = bias[ubase + j];
#pragma unroll
  for (int i = 0; i < 4; ++i) {
    const long row = row0 + tr + 64 * i;
    float4 o0, o1;
    o0.x = acc[i][0] + bv[0]; o0.y = acc[i][1] + bv[1];
    o0.z = acc[i][2] + bv[2]; o0.w = acc[i][3] + bv[3];
    o1.x = acc[i][4] + bv[4]; o1.y = acc[i][5] + bv[5];
    o1.z = acc[i][6] + bv[6]; o1.w = acc[i][7] + bv[7];
    *(float4*)(out + row * UU + ubase) = o0;
    *(float4*)(out + row * UU + ubase + 4) = o1;
  }
}

// ---------------------------------------------------------------------------
// K2: Viterbi forward — DPP edition. One wave per chain.
// 64 lanes = 4 rows of 16. Two alpha copies live in the wave, in one of two
// layouts (row contents by row index r=0..3):
//   layout S: [alpha_lo, alpha_hi, alpha_hi, alpha_lo]
//   layout D: [alpha_lo, alpha_hi, alpha_lo, alpha_hi]
// A step from layout S ("S-step") has lane (r,q) compute the partial max over
// its row's 16 v-sources (15 DPP row_ror + identity, with T pre-permuted into
// per-lane tables tvS/tvD) for target u: tgtS = (bit4)*16+q. The two partials
// per target sit at lanes l and l^32 -> ONE ds_bpermute combines them and the
// resulting register layout is exactly layout D. A D-step pairs via l^48 and
// yields layout S. So the only DS op per step is one bpermute (was 17).
// DPP rotate direction is probed at runtime (direction-proof tables).
// Logits: 16-deep double-buffered register prefetch, per-lane column matches
// the step-parity target. Alpha rows stored from lanes<32 (tgt==lane there).
// ---------------------------------------------------------------------------
__global__ __launch_bounds__(64) void k2_forward(float* __restrict__ lb,
                                                 const float* __restrict__ trans,
                                                 const int* __restrict__ nwords,
                                                 float* __restrict__ score) {
  const int b = blockIdx.x;
  const int lane = threadIdx.x;
  const int q = lane & 15;
  const int bit4 = (lane >> 4) & 1;
  const int bit5 = (lane >> 5) & 1;
  const int hiS = bit4 ^ bit5;      // source-half flag in layout S (rows 0,3 lo; 1,2 hi)
  const int hiD = bit4;             // source-half flag in layout D (rows 0,2 lo; 1,3 hi)
  const int tgtS = bit4 * 16 + q;   // this lane's target column on S-steps
  const int tgtD = hiS * 16 + q;    // this lane's target column on D-steps

  // Probe DPP row_ror:1 direction: does pos q read (q+1)&15 or (q-1)&15?
  const int probe = __builtin_amdgcn_update_dpp(0, q, 0x121, 0xF, 0xF, 0);
  const bool dirp = (probe == ((q + 1) & 15));

  float tvS[16], tvD[16];
#pragma unroll
  for (int s = 0; s < 16; ++s) {
    const int rp = dirp ? ((q + s) & 15) : ((q - s) & 15);
    tvS[s] = trans[(hiS * 16 + rp) * UU + tgtS];
    tvD[s] = trans[(hiD * 16 + rp) * UU + tgtD];
  }

  float* base = lb + (size_t)b * TT * UU;
  const int nw = nwords[b];
  const int idx32 = (lane ^ 32) << 2;
  const int idx48 = (lane ^ 48) << 2;

  float P = base[hiS * 16 + q];  // alpha0 in layout S (row0 = logits+bias)

  float bufA[16], bufB[16];
#pragma unroll
  for (int i = 0; i < 16; ++i) {
    int r = 1 + i; if (r > TT - 1) r = TT - 1;
    const int col = (i & 1) ? tgtD : tgtS;  // t=1+i: i even -> odd t -> S-step
    bufA[i] = base[(size_t)r * UU + col];
  }

#define ROT(S) \
  __int_as_float(__builtin_amdgcn_update_dpp(0, __float_as_int(P), 0x120 + (S), 0xF, 0xF, 0))

#define K2_STEP(tval, lg, TV, XIDX)                                           \
  {                                                                           \
    const float c0 = P + (TV)[0];                                             \
    const float c1 = ROT(1) + (TV)[1];                                        \
    const float c2 = ROT(2) + (TV)[2];                                        \
    const float c3 = ROT(3) + (TV)[3];                                        \
    const float c4 = ROT(4) + (TV)[4];                                        \
    const float c5 = ROT(5) + (TV)[5];                                        \
    const float c6 = ROT(6) + (TV)[6];                                        \
    const float c7 = ROT(7) + (TV)[7];                                        \
    const float c8 = ROT(8) + (TV)[8];                                        \
    const float c9 = ROT(9) + (TV)[9];                                        \
    const float c10 = ROT(10) + (TV)[10];                                     \
    const float c11 = ROT(11) + (TV)[11];                                     \
    const float c12 = ROT(12) + (TV)[12];                                     \
    const float c13 = ROT(13) + (TV)[13];                                     \
    const float c14 = ROT(14) + (TV)[14];                                     \
    const float c15 = ROT(15) + (TV)[15];                                     \
    const float a0 = fmaxf(c0, c1), a1 = fmaxf(c2, c3);                       \
    const float a2 = fmaxf(c4, c5), a3 = fmaxf(c6, c7);                       \
    const float a4 = fmaxf(c8, c9), a5 = fmaxf(c10, c11);                     \
    const float a6 = fmaxf(c12, c13), a7 = fmaxf(c14, c15);                   \
    const float b0 = fmaxf(a0, a1), b1 = fmaxf(a2, a3);                       \
    const float b2 = fmaxf(a4, a5), b3 = fmaxf(a6, a7);                       \
    const float pm = fmaxf(fmaxf(b0, b1), fmaxf(b2, b3));                     \
    const int po = __builtin_amdgcn_ds_bpermute((XIDX), __float_as_int(pm));  \
    P = fmaxf(pm, __int_as_float(po)) + (lg);                                 \
    if (lane < 32) base[(size_t)(tval)*UU + lane] = P;                        \
  }

  for (int tc = 1; tc < nw; tc += 32) {
    // prefetch bufB = rows [tc+16, tc+32)
#pragma unroll
    for (int i = 0; i < 16; ++i) {
      int r = tc + 16 + i; if (r > TT - 1) r = TT - 1;
      const int col = (i & 1) ? tgtD : tgtS;
      bufB[i] = base[(size_t)r * UU + col];
    }
    // body A: steps tc .. tc+15 (tc odd: i even -> S-step, i odd -> D-step)
#pragma unroll
    for (int i = 0; i < 16; ++i) {
      const int t = tc + i;
      if (t < nw) {
        if ((i & 1) == 0) K2_STEP(t, bufA[i], tvS, idx32)
        else              K2_STEP(t, bufA[i], tvD, idx48)
      }
    }
    // prefetch bufA = rows [tc+32, tc+48)
#pragma unroll
    for (int i = 0; i < 16; ++i) {
      int r = tc + 32 + i; if (r > TT - 1) r = TT - 1;
      const int col = (i & 1) ? tgtD : tgtS;
      bufA[i] = base[(size_t)r * UU + col];
    }
    // body B: steps tc+16 .. tc+31 (same parity mapping: 16 is even)
#pragma unroll
    for (int i = 0; i < 16; ++i) {
      const int t = tc + 16 + i;
      if (t < nw) {
        if ((i & 1) == 0) K2_STEP(t, bufB[i], tvS, idx32)
        else              K2_STEP(t, bufB[i], tvD, idx48)
      }
    }
  }
#undef K2_STEP
#undef ROT

  // All 64 lanes hold alpha_{nw-1} values (each state twice) -> plain reduce.
  float sm = P;
#pragma unroll
  for (int s = 32; s; s >>= 1) sm = fmaxf(sm, __shfl_xor(sm, s));
  if (lane == 0) score[b] = sm;
}

// ---------------------------------------------------------------------------
// K3: backpointers, fully parallel from stored alpha rows.
// ---------------------------------------------------------------------------
__global__ __launch_bounds__(256) void k3_bp(const float* __restrict__ lb,
                                             const float* __restrict__ trans,
                                             const int* __restrict__ nwords,
                                             unsigned char* __restrict__ bp) {
  __shared__ float as[129 * 32];
  __shared__ float ts[32 * 32];
  const int b = blockIdx.x >> 4;
  const int c = blockIdx.x & 15;
  const int t0 = 128 * c;
  const int tid = threadIdx.x;
  const float* base = lb + (size_t)b * TT * UU;
  const int nw = nwords[b];

  for (int idx = tid; idx < 129 * 32; idx += 256) {
    const int gidx = (t0 - 1) * 32 + idx;
    as[idx] = (gidx >= 0 && gidx < TT * UU) ? base[gidx] : 0.0f;
  }
  for (int idx = tid; idx < 1024; idx += 256) ts[idx] = trans[idx];
  __syncthreads();

  const int u = tid & 31;
  const int tg = tid >> 5;
  unsigned char* bpu = bp + ((size_t)b * 32 + u) * TT;

#pragma unroll 1
  for (int q = 0; q < 4; ++q) {
    const int tl0 = tg * 16 + q * 4;
    unsigned int pack = 0;
#pragma unroll
    for (int e = 0; e < 4; ++e) {
      const int tl = tl0 + e;
      const int t = t0 + tl;
      int idx;
      if (t >= 1 && t < nw) {
        float m = as[tl * 32 + 0] + ts[0 * 32 + u];
        idx = 0;
#pragma unroll
        for (int v = 1; v < 32; ++v) {
          const float cv = as[tl * 32 + v] + ts[v * 32 + u];
          if (cv > m) { m = cv; idx = v; }
        }
      } else {
        idx = u;
      }
      pack |= ((unsigned int)idx) << (8 * e);
    }
    *(unsigned int*)(bpu + t0 + tl0) = pack;
  }
}

// ---------------------------------------------------------------------------
// K4: backtrace, one wave per chain; bp chunks held in VGPRs, tag via readlane.
// ---------------------------------------------------------------------------
__global__ __launch_bounds__(64) void k4_backtrace(const float* __restrict__ lb,
                                                   const unsigned char* __restrict__ bp,
                                                   const int* __restrict__ nwords,
                                                   int* __restrict__ pred) {
  const int b = blockIdx.x;
  const int lane = threadIdx.x;
  const int u = lane & 31;
  const int h = lane >> 5;
  const int nw = nwords[b];

  const float a = lb[((size_t)b * TT + (nw - 1)) * UU + u];
  float m = a;
#pragma unroll
  for (int s = 32; s; s >>= 1) m = fmaxf(m, __shfl_xor(m, s));
  const unsigned long long mask = __ballot(lane < 32 && a == m);
  int tag = __ffsll((unsigned long long)mask) - 1;
  tag = __builtin_amdgcn_readfirstlane(tag);

  int* predb = pred + b * TT;
  for (int p = nw - 1 + lane; p < TT; p += 64) predb[p] = tag;
  if (nw < 2) return;

  const unsigned char* bpb = bp + (size_t)b * 32 * TT;
  const int pcmax = (nw - 2) >> 6;
  const int thi_top = nw - 1;

  int wprev0 = 0;
  {
    const int toff = (pcmax + 1) * 64;
    if (toff < TT) wprev0 = *(const int*)(bpb + (size_t)u * TT + toff);
  }

  for (int pc = pcmax; pc >= 0; --pc) {
    int wreg[8];
#pragma unroll
    for (int j = 0; j < 8; ++j)
      wreg[j] = *(const int*)(bpb + (size_t)u * TT + pc * 64 + 4 * (h * 8 + j));
    const int thi = (pc == pcmax) ? thi_top : (pc * 64 + 64);
    int predv = 0;

    if (pc * 64 + 64 <= thi) {
      const int val = __builtin_amdgcn_readlane(wprev0, tag);
      tag = __builtin_amdgcn_readfirstlane(val & 0xFF);
      if (lane == 63) predv = tag;
    }
#pragma unroll
    for (int lt = 63; lt >= 1; --lt) {
      if (pc * 64 + lt <= thi) {
        const int d = lt >> 2, byte = lt & 3;
        const int hs = d >> 3, j = d & 7;
        const int val = __builtin_amdgcn_readlane(wreg[j], hs * 32 + tag);
        tag = __builtin_amdgcn_readfirstlane((val >> (8 * byte)) & 0xFF);
        if (lane == lt - 1) predv = tag;
      }
    }
    const int lim = thi - pc * 64;
    if (lane < lim) predb[pc * 64 + lane] = predv;
    wprev0 = wreg[0];
  }
}

// ---------------------------------------------------------------------------
extern "C" void kernel_launch(void* const* d_in, const int* in_sizes, int n_in,
                              void* d_out, int out_size, void* d_ws, size_t ws_size,
                              hipStream_t stream) {
  const float* x = (const float*)d_in[0];
  const int* nwords = (const int*)d_in[1];
  const float* kern = (const float*)d_in[2];
  const float* chain = (const float*)d_in[3];
  const float* bias = (const float*)d_in[4];

  float* logits = (float*)d_ws;                                        // 16 MB
  unsigned char* bp = (unsigned char*)d_ws + (size_t)BB * TT * UU * 4; // +4 MB

  int* pred = (int*)d_out;
  float* score = (float*)d_out + (size_t)BB * TT;

  k1_logits<<<dim3(512), dim3(256), 0, stream>>>(x, kern, bias, logits);
  k2_forward<<<dim3(BB), dim3(64), 0, stream>>>(logits, chain, nwords, score);
  k3_bp<<<dim3(BB * 16), dim3(256), 0, stream>>>(logits, chain, nwords, bp);
  k4_backtrace<<<dim3(BB), dim3(64), 0, stream>>>(logits, bp, nwords, pred);
}

// Round 4
// 625.620 us; speedup vs baseline: 2.3653x; 1.1004x over previous
//
#include <hip/hip_runtime.h>

#define BB 64
#define TT 2048
#define DD 512
#define UU 32

// ---------------------------------------------------------------------------
// K1: logits[b,t,u] = sum_k x[b,t,k]*kernel[k,u] + bias[u]   (unchanged)
// ---------------------------------------------------------------------------
__global__ __launch_bounds__(256) void k1_logits(const float* __restrict__ x,
                                                 const float* __restrict__ w,
                                                 const float* __restrict__ bias,
                                                 float* __restrict__ out) {
  __shared__ float xs[256 * 34];
  __shared__ float wsh[32 * 36];
  const int tid = threadIdx.x;
  const long row0 = (long)blockIdx.x * 256;
  const int tr = tid >> 2;
  const int tc = tid & 3;
  const int ubase = tc * 8;
  const int sr = tid >> 3;
  const int sc = (tid & 7) * 4;

  float acc[4][8];
#pragma unroll
  for (int i = 0; i < 4; ++i)
#pragma unroll
    for (int j = 0; j < 8; ++j) acc[i][j] = 0.0f;

  for (int kc = 0; kc < DD; kc += 32) {
#pragma unroll
    for (int p = 0; p < 8; ++p) {
      const int r = p * 32 + sr;
      const float4 v = *(const float4*)(x + (row0 + r) * DD + kc + sc);
      *(float2*)(&xs[r * 34 + sc]) = make_float2(v.x, v.y);
      *(float2*)(&xs[r * 34 + sc + 2]) = make_float2(v.z, v.w);
    }
    {
      const int k = tid >> 3;
      const int uu4 = (tid & 7) * 4;
      const float4 v = *(const float4*)(w + (size_t)(kc + k) * UU + uu4);
      *(float4*)(&wsh[k * 36 + uu4]) = v;
    }
    __syncthreads();
#pragma unroll
    for (int k = 0; k < 32; ++k) {
      const float4 w0 = *(const float4*)(&wsh[k * 36 + ubase]);
      const float4 w1 = *(const float4*)(&wsh[k * 36 + ubase + 4]);
      const float wv[8] = {w0.x, w0.y, w0.z, w0.w, w1.x, w1.y, w1.z, w1.w};
#pragma unroll
      for (int i = 0; i < 4; ++i) {
        const float xv = xs[(tr + 64 * i) * 34 + k];
#pragma unroll
        for (int j = 0; j < 8; ++j) acc[i][j] = fmaf(xv, wv[j], acc[i][j]);
      }
    }
    __syncthreads();
  }
  float bv[8];
#pragma unroll
  for (int j = 0; j < 8; ++j) bv[j] = bias[ubase + j];
#pragma unroll
  for (int i = 0; i < 4; ++i) {
    const long row = row0 + tr + 64 * i;
    float4 o0, o1;
    o0.x = acc[i][0] + bv[0]; o0.y = acc[i][1] + bv[1];
    o0.z = acc[i][2] + bv[2]; o0.w = acc[i][3] + bv[3];
    o1.x = acc[i][4] + bv[4]; o1.y = acc[i][5] + bv[5];
    o1.z = acc[i][6] + bv[6]; o1.w = acc[i][7] + bv[7];
    *(float4*)(out + row * UU + ubase) = o0;
    *(float4*)(out + row * UU + ubase + 4) = o1;
  }
}

// ---------------------------------------------------------------------------
// K2: Viterbi forward — permlane-swap edition. One wave per chain.
// Uniform S-layout scheme: [alpha_lo, alpha_hi, alpha_hi, alpha_lo] by row.
// Step: 15 DPP row_ror + adds + max-tree -> partial pm (target tgtS=bit4*16+q,
// pairs at l^32). Combine: v_permlane32_swap(pm,pm), max of the two results
// (direction-proof). Add logit (col tgtS) -> layout D. Restore layout S with
// v_permlane16_swap + cndmasks (probed masks). Store from ALL 64 lanes at col
// cstoS=hiS*16+q (pairs l/l^48 write same value to same address - benign).
// No nw-dependence: all 2047 steps run; rows >= nw hold garbage (never read).
// Runtime-probed; falls back to the R2 bpermute scheme if probes fail.
// ---------------------------------------------------------------------------
__global__ __launch_bounds__(64) void k2_forward(float* __restrict__ lb,
                                                 const float* __restrict__ trans,
                                                 const int* __restrict__ nwords) {
  const int lane = threadIdx.x;
  const int q = lane & 15;
  const int bit4 = (lane >> 4) & 1;
  const int bit5v = (lane >> 5) & 1;
  const int hiS = bit4 ^ bit5v;
  const int tgtS = bit4 * 16 + q;   // target col on S-steps (= content col in layout D)
  const int cstoS = hiS * 16 + q;   // content/store col in layout S (= D-step target)

  // DPP row_ror direction probe (verified working in R2)
  const int probe = __builtin_amdgcn_update_dpp(0, q, 0x121, 0xF, 0xF, false);
  const bool dirp = (probe == ((q + 1) & 15));

  float tvS[16];
#pragma unroll
  for (int s = 0; s < 16; ++s) {
    const int rp = dirp ? ((q + s) & 15) : ((q - s) & 15);
    tvS[s] = trans[(hiS * 16 + rp) * UU + tgtS];
  }

  const int b = blockIdx.x;
  float* base = lb + (size_t)b * TT * UU;
  float P = base[cstoS];  // alpha0 in layout S

  float bufA[16], bufB[16];

#define ROTF(S) \
  __int_as_float(__builtin_amdgcn_update_dpp(0, __float_as_int(P), 0x120 + (S), 0xF, 0xF, true))

#define K2_TREE                                                              \
    const float c0 = P + tvS[0];                                             \
    const float c1 = ROTF(1) + tvS[1];                                       \
    const float c2 = ROTF(2) + tvS[2];                                       \
    const float c3 = ROTF(3) + tvS[3];                                       \
    const float c4 = ROTF(4) + tvS[4];                                       \
    const float c5 = ROTF(5) + tvS[5];                                       \
    const float c6 = ROTF(6) + tvS[6];                                       \
    const float c7 = ROTF(7) + tvS[7];                                       \
    const float c8 = ROTF(8) + tvS[8];                                       \
    const float c9 = ROTF(9) + tvS[9];                                       \
    const float c10 = ROTF(10) + tvS[10];                                    \
    const float c11 = ROTF(11) + tvS[11];                                    \
    const float c12 = ROTF(12) + tvS[12];                                    \
    const float c13 = ROTF(13) + tvS[13];                                    \
    const float c14 = ROTF(14) + tvS[14];                                    \
    const float c15 = ROTF(15) + tvS[15];                                    \
    const float d0 = fmaxf(fmaxf(c0, c1), c2);                               \
    const float d1 = fmaxf(fmaxf(c3, c4), c5);                               \
    const float d2 = fmaxf(fmaxf(c6, c7), c8);                               \
    const float d3 = fmaxf(fmaxf(c9, c10), c11);                             \
    const float d4 = fmaxf(fmaxf(c12, c13), c14);                            \
    const float e0 = fmaxf(fmaxf(d0, d1), d2);                               \
    const float e1 = fmaxf(fmaxf(d3, d4), c15);                              \
    const float pm = fmaxf(e0, e1);

#if __has_builtin(__builtin_amdgcn_permlane32_swap) && __has_builtin(__builtin_amdgcn_permlane16_swap)
  typedef unsigned int v2u __attribute__((ext_vector_type(2)));
  // Probe swap semantics with lane ids; build per-lane select masks.
  v2u p32 = __builtin_amdgcn_permlane32_swap((unsigned)lane, (unsigned)lane, false, false);
  v2u p16 = __builtin_amdgcn_permlane16_swap((unsigned)lane, (unsigned)lane, false, false);
  const bool c32ok = ((int)p32.x == (lane ^ 32)) || ((int)p32.y == (lane ^ 32));
  const bool c16ok = ((int)p16.x == (lane ^ 16)) || ((int)p16.y == (lane ^ 16));
  const bool m16sel = ((int)p16.x == (lane ^ 16));
  const bool okSwap = (__ballot(c32ok) == ~0ull) && (__ballot(c16ok) == ~0ull);

#define K2_FSTEP(tval, lg) do {                                              \
    K2_TREE                                                                  \
    v2u s32 = __builtin_amdgcn_permlane32_swap(__float_as_uint(pm),          \
                                               __float_as_uint(pm), false, false); \
    const float pd = fmaxf(__uint_as_float(s32.x), __uint_as_float(s32.y)) + (lg); \
    v2u s16 = __builtin_amdgcn_permlane16_swap(__float_as_uint(pd),          \
                                               __float_as_uint(pd), false, false); \
    const float cx = m16sel ? __uint_as_float(s16.x) : __uint_as_float(s16.y); \
    P = bit5v ? cx : pd;                                                     \
    base[(size_t)(tval) * UU + cstoS] = P;                                   \
  } while (0)

  if (okSwap) {
#pragma unroll
    for (int i = 0; i < 16; ++i) bufA[i] = base[(size_t)(1 + i) * UU + tgtS];
#pragma unroll 1
    for (int tc = 1; tc <= 1985; tc += 32) {
#pragma unroll
      for (int i = 0; i < 16; ++i) bufB[i] = base[(size_t)(tc + 16 + i) * UU + tgtS];
#pragma unroll
      for (int i = 0; i < 16; ++i) K2_FSTEP(tc + i, bufA[i]);
#pragma unroll
      for (int i = 0; i < 16; ++i) bufA[i] = base[(size_t)(tc + 32 + i) * UU + tgtS];
#pragma unroll
      for (int i = 0; i < 16; ++i) K2_FSTEP(tc + 16 + i, bufB[i]);
    }
    // peeled tail: tc = 2017; bufA holds rows 2017..2032
#pragma unroll
    for (int i = 0; i < 16; ++i) {
      int r = 2033 + i; if (r > TT - 1) r = TT - 1;
      bufB[i] = base[(size_t)r * UU + tgtS];
    }
#pragma unroll
    for (int i = 0; i < 16; ++i) K2_FSTEP(2017 + i, bufA[i]);
#pragma unroll
    for (int i = 0; i < 15; ++i) K2_FSTEP(2033 + i, bufB[i]);
    return;
  }
#endif

  // ---------------- fallback: R2 bpermute alternating S/D scheme ----------
  {
    float tvD[16];
#pragma unroll
    for (int s = 0; s < 16; ++s) {
      const int rp = dirp ? ((q + s) & 15) : ((q - s) & 15);
      tvD[s] = trans[(bit4 * 16 + rp) * UU + cstoS];
    }
    const int idx32 = (lane ^ 32) << 2;
    const int idx48 = (lane ^ 48) << 2;

#define K2_BSTEP(tval, lg, TVHI, XIDX, SCOL) do {                            \
    K2_TREE                                                                  \
    (void)pm;                                                                \
    float pm2 = pm;                                                          \
    if (&(TVHI)[0] != &tvS[0]) {                                             \
      /* recompute adds with tvD table */                                    \
      const float g0 = P + (TVHI)[0];                                        \
      const float g1 = ROTF(1) + (TVHI)[1];                                  \
      const float g2 = ROTF(2) + (TVHI)[2];                                  \
      const float g3 = ROTF(3) + (TVHI)[3];                                  \
      const float g4 = ROTF(4) + (TVHI)[4];                                  \
      const float g5 = ROTF(5) + (TVHI)[5];                                  \
      const float g6 = ROTF(6) + (TVHI)[6];                                  \
      const float g7 = ROTF(7) + (TVHI)[7];                                  \
      const float g8 = ROTF(8) + (TVHI)[8];                                  \
      const float g9 = ROTF(9) + (TVHI)[9];                                  \
      const float g10 = ROTF(10) + (TVHI)[10];                               \
      const float g11 = ROTF(11) + (TVHI)[11];                               \
      const float g12 = ROTF(12) + (TVHI)[12];                               \
      const float g13 = ROTF(13) + (TVHI)[13];                               \
      const float g14 = ROTF(14) + (TVHI)[14];                               \
      const float g15 = ROTF(15) + (TVHI)[15];                               \
      const float h0 = fmaxf(fmaxf(g0, g1), g2);                             \
      const float h1 = fmaxf(fmaxf(g3, g4), g5);                             \
      const float h2 = fmaxf(fmaxf(g6, g7), g8);                             \
      const float h3 = fmaxf(fmaxf(g9, g10), g11);                           \
      const float h4 = fmaxf(fmaxf(g12, g13), g14);                          \
      const float k0 = fmaxf(fmaxf(h0, h1), h2);                             \
      const float k1 = fmaxf(fmaxf(h3, h4), g15);                            \
      pm2 = fmaxf(k0, k1);                                                   \
    }                                                                        \
    const int po = __builtin_amdgcn_ds_bpermute((XIDX), __float_as_int(pm2));\
    P = fmaxf(pm2, __int_as_float(po)) + (lg);                               \
    base[(size_t)(tval) * UU + (SCOL)] = P;                                  \
  } while (0)

#pragma unroll
    for (int i = 0; i < 16; ++i)
      bufA[i] = base[(size_t)(1 + i) * UU + ((i & 1) ? cstoS : tgtS)];
#pragma unroll 1
    for (int tc = 1; tc <= 1985; tc += 32) {
#pragma unroll
      for (int i = 0; i < 16; ++i)
        bufB[i] = base[(size_t)(tc + 16 + i) * UU + ((i & 1) ? cstoS : tgtS)];
#pragma unroll
      for (int i = 0; i < 16; ++i) {
        if ((i & 1) == 0) K2_BSTEP(tc + i, bufA[i], tvS, idx32, tgtS);
        else              K2_BSTEP(tc + i, bufA[i], tvD, idx48, cstoS);
      }
#pragma unroll
      for (int i = 0; i < 16; ++i)
        bufA[i] = base[(size_t)(tc + 32 + i) * UU + ((i & 1) ? cstoS : tgtS)];
#pragma unroll
      for (int i = 0; i < 16; ++i) {
        if ((i & 1) == 0) K2_BSTEP(tc + 16 + i, bufB[i], tvS, idx32, tgtS);
        else              K2_BSTEP(tc + 16 + i, bufB[i], tvD, idx48, cstoS);
      }
    }
#pragma unroll
    for (int i = 0; i < 16; ++i) {
      int r = 2033 + i; if (r > TT - 1) r = TT - 1;
      bufB[i] = base[(size_t)r * UU + ((i & 1) ? cstoS : tgtS)];
    }
#pragma unroll
    for (int i = 0; i < 16; ++i) {
      if ((i & 1) == 0) K2_BSTEP(2017 + i, bufA[i], tvS, idx32, tgtS);
      else              K2_BSTEP(2017 + i, bufA[i], tvD, idx48, cstoS);
    }
#pragma unroll
    for (int i = 0; i < 15; ++i) {
      if ((i & 1) == 0) K2_BSTEP(2033 + i, bufB[i], tvS, idx32, tgtS);
      else              K2_BSTEP(2033 + i, bufB[i], tvD, idx48, cstoS);
    }
  }
}

// ---------------------------------------------------------------------------
// K3: backpointers, fully parallel from stored alpha rows.  (unchanged)
// ---------------------------------------------------------------------------
__global__ __launch_bounds__(256) void k3_bp(const float* __restrict__ lb,
                                             const float* __restrict__ trans,
                                             const int* __restrict__ nwords,
                                             unsigned char* __restrict__ bp) {
  __shared__ float as[129 * 32];
  __shared__ float ts[32 * 32];
  const int b = blockIdx.x >> 4;
  const int c = blockIdx.x & 15;
  const int t0 = 128 * c;
  const int tid = threadIdx.x;
  const float* base = lb + (size_t)b * TT * UU;
  const int nw = nwords[b];

  for (int idx = tid; idx < 129 * 32; idx += 256) {
    const int gidx = (t0 - 1) * 32 + idx;
    as[idx] = (gidx >= 0 && gidx < TT * UU) ? base[gidx] : 0.0f;
  }
  for (int idx = tid; idx < 1024; idx += 256) ts[idx] = trans[idx];
  __syncthreads();

  const int u = tid & 31;
  const int tg = tid >> 5;
  unsigned char* bpu = bp + ((size_t)b * 32 + u) * TT;

#pragma unroll 1
  for (int qq = 0; qq < 4; ++qq) {
    const int tl0 = tg * 16 + qq * 4;
    unsigned int pack = 0;
#pragma unroll
    for (int e = 0; e < 4; ++e) {
      const int tl = tl0 + e;
      const int t = t0 + tl;
      int idx;
      if (t >= 1 && t < nw) {
        float m = as[tl * 32 + 0] + ts[0 * 32 + u];
        idx = 0;
#pragma unroll
        for (int v = 1; v < 32; ++v) {
          const float cv = as[tl * 32 + v] + ts[v * 32 + u];
          if (cv > m) { m = cv; idx = v; }
        }
      } else {
        idx = u;
      }
      pack |= ((unsigned int)idx) << (8 * e);
    }
    *(unsigned int*)(bpu + t0 + tl0) = pack;
  }
}

// ---------------------------------------------------------------------------
// K4: backtrace + best_score. One wave per chain.
// ---------------------------------------------------------------------------
__global__ __launch_bounds__(64) void k4_backtrace(const float* __restrict__ lb,
                                                   const unsigned char* __restrict__ bp,
                                                   const int* __restrict__ nwords,
                                                   int* __restrict__ pred,
                                                   float* __restrict__ score) {
  const int b = blockIdx.x;
  const int lane = threadIdx.x;
  const int u = lane & 31;
  const int h = lane >> 5;
  const int nw = nwords[b];

  const float a = lb[((size_t)b * TT + (nw - 1)) * UU + u];
  float m = a;
#pragma unroll
  for (int s = 32; s; s >>= 1) m = fmaxf(m, __shfl_xor(m, s));
  if (lane == 0) score[b] = m;
  const unsigned long long mask = __ballot(lane < 32 && a == m);
  int tag = __ffsll((unsigned long long)mask) - 1;
  tag = __builtin_amdgcn_readfirstlane(tag);

  int* predb = pred + b * TT;
  for (int p = nw - 1 + lane; p < TT; p += 64) predb[p] = tag;
  if (nw < 2) return;

  const unsigned char* bpb = bp + (size_t)b * 32 * TT;
  const int pcmax = (nw - 2) >> 6;
  const int thi_top = nw - 1;

  int wprev0 = 0;
  {
    const int toff = (pcmax + 1) * 64;
    if (toff < TT) wprev0 = *(const int*)(bpb + (size_t)u * TT + toff);
  }

  for (int pc = pcmax; pc >= 0; --pc) {
    int wreg[8];
#pragma unroll
    for (int j = 0; j < 8; ++j)
      wreg[j] = *(const int*)(bpb + (size_t)u * TT + pc * 64 + 4 * (h * 8 + j));
    const int thi = (pc == pcmax) ? thi_top : (pc * 64 + 64);
    int predv = 0;

    if (pc * 64 + 64 <= thi) {
      const int val = __builtin_amdgcn_readlane(wprev0, tag);
      tag = __builtin_amdgcn_readfirstlane(val & 0xFF);
      if (lane == 63) predv = tag;
    }
#pragma unroll
    for (int lt = 63; lt >= 1; --lt) {
      if (pc * 64 + lt <= thi) {
        const int d = lt >> 2, byte = lt & 3;
        const int hs = d >> 3, j = d & 7;
        const int val = __builtin_amdgcn_readlane(wreg[j], hs * 32 + tag);
        tag = __builtin_amdgcn_readfirstlane((val >> (8 * byte)) & 0xFF);
        if (lane == lt - 1) predv = tag;
      }
    }
    const int lim = thi - pc * 64;
    if (lane < lim) predb[pc * 64 + lane] = predv;
    wprev0 = wreg[0];
  }
}

// ---------------------------------------------------------------------------
extern "C" void kernel_launch(void* const* d_in, const int* in_sizes, int n_in,
                              void* d_out, int out_size, void* d_ws, size_t ws_size,
                              hipStream_t stream) {
  const float* x = (const float*)d_in[0];
  const int* nwords = (const int*)d_in[1];
  const float* kern = (const float*)d_in[2];
  const float* chain = (const float*)d_in[3];
  const float* bias = (const float*)d_in[4];

  float* logits = (float*)d_ws;                                        // 16 MB
  unsigned char* bp = (unsigned char*)d_ws + (size_t)BB * TT * UU * 4; // +4 MB

  int* pred = (int*)d_out;
  float* score = (float*)d_out + (size_t)BB * TT;

  k1_logits<<<dim3(512), dim3(256), 0, stream>>>(x, kern, bias, logits);
  k2_forward<<<dim3(BB), dim3(64), 0, stream>>>(logits, chain, nwords);
  k3_bp<<<dim3(BB * 16), dim3(256), 0, stream>>>(logits, chain, nwords, bp);
  k4_backtrace<<<dim3(BB), dim3(64), 0, stream>>>(logits, bp, nwords, pred, score);
}